// Round 1
// baseline (540.281 us; speedup 1.0000x reference)
//
#include <hip/hip_runtime.h>

// Tree-RNN: h = relu(leaf_seqs @ We^T + be); 13x: h = relu(pairs @ W^T + b); logits = h @ Wp^T + bp
// All fp32 (no fp32 MFMA on CDNA4 -> vector-FMA bound, floor ~43us for the 6.7 GFLOP leaf GEMM).
//
// Pipeline:
//  K0 transpose_we : We[100][4096] -> WeT[4096][112] (two 50-col groups padded to 56 for 16B align)
//  K1 leaf_gemm    : 256 blocks (1/CU), block tile 32 rows x 100 cols, K=4096 sliced 8-way in-block,
//                    per-thread 2x50 accumulators, XOR-swizzled k-major A tile in LDS,
//                    register-prefetch pipeline, LDS k-slice reduction + bias + relu -> h0[8192][100]
//  K2-K4 tree_levels: block owns 32 (or 8) consecutive vectors, descends 5 (or 3) levels in LDS;
//                    W[100][200] cached in VGPRs per (j,s)-thread, children via broadcast LDS reads
//  K5 proj         : logits[2]

__global__ __launch_bounds__(256) void transpose_we(const float* __restrict__ We,
                                                    float* __restrict__ WeT) {
  int idx = blockIdx.x * 256 + threadIdx.x;
  if (idx >= 4096 * 112) return;
  int k = idx / 112;
  int col = idx - k * 112;
  int cg = col / 56;
  int jj = col - cg * 56;
  float v = 0.f;
  if (jj < 50) v = We[(size_t)(cg * 50 + jj) * 4096 + k];
  WeT[idx] = v;
}

// ---------------------------------------------------------------------------
// K1: h0[r][j] = relu(be[j] + sum_k A[r][k] * WeT[k][j])
// grid 256 blocks x 256 threads. Block: rows [32b, 32b+32), all 100 cols.
// Thread (rt 0..15, c 0..1, ks 0..7): rows {2rt, 2rt+1}, cols [50c, 50c+50), k-slice ks.
// ---------------------------------------------------------------------------
__global__ __launch_bounds__(256, 1) void leaf_gemm(const float* __restrict__ A,
                                                    const float* __restrict__ WeT,
                                                    const float* __restrict__ be,
                                                    float* __restrict__ h0) {
  // LDS overlay: tiles (As 2048 + Ws 7168 floats) vs reduce scratch (4*3200 floats)
  __shared__ __align__(16) float lds[12800];
  float* As = lds;          // [64][32] k-major, column XOR-swizzled
  float* Ws = lds + 2048;   // [64][112]

  const int tid = threadIdx.x;
  const int rt = tid & 15;
  const int c = (tid >> 4) & 1;
  const int ks = tid >> 5;
  const int r0 = blockIdx.x * 32;

  float acc0[50], acc1[50];
#pragma unroll
  for (int i = 0; i < 50; ++i) { acc0[i] = 0.f; acc1[i] = 0.f; }

  float4 rA[2];  // A-tile prefetch regs (2048 floats / 256 thr = 2 float4)
  float4 rW[7];  // W-tile prefetch regs (7168 floats / 256 thr = 7 float4)

  auto load_tile = [&](int t) {
    const int kb = t * 64;
#pragma unroll
    for (int v = 0; v < 2; ++v) {
      int lin = v * 256 + tid;
      int q = lin & 15;        // float4 index along k (16 per row)
      int rr = lin >> 4;       // row in tile 0..31
      rA[v] = *(const float4*)(A + (size_t)(r0 + rr) * 4096 + kb + 4 * q);
    }
    const float4* wg = (const float4*)(WeT + (size_t)kb * 112);
#pragma unroll
    for (int v = 0; v < 7; ++v) rW[v] = wg[v * 256 + tid];
  };

  auto store_tile = [&]() {
#pragma unroll
    for (int v = 0; v < 2; ++v) {
      int lin = v * 256 + tid;
      int q = lin & 15;
      int rr = lin >> 4;
      const float* f = (const float*)&rA[v];
#pragma unroll
      for (int u = 0; u < 4; ++u) {
        int kk = 4 * q + u;
        int col = rr ^ ((2 * (kk >> 2)) & 31);  // swizzle: write <=2-way, read conflict-free
        As[kk * 32 + col] = f[u];
      }
    }
    float4* wl = (float4*)Ws;
#pragma unroll
    for (int v = 0; v < 7; ++v) wl[v * 256 + tid] = rW[v];
  };

  load_tile(0);
  for (int t = 0; t < 64; ++t) {
    __syncthreads();  // previous tile's compute done reading LDS
    store_tile();
    __syncthreads();
    if (t + 1 < 64) load_tile(t + 1);  // in flight during compute below
#pragma unroll
    for (int i = 0; i < 8; ++i) {
      const int kk = ks * 8 + i;
      const int colbase = (2 * rt) ^ ((2 * (kk >> 2)) & 31);  // even, pair stays contiguous
      float2 a = *(const float2*)&As[kk * 32 + colbase];      // rows 2rt, 2rt+1
      const float* wrow = Ws + kk * 112 + c * 56;             // broadcast reads
#pragma unroll
      for (int q2 = 0; q2 < 12; ++q2) {
        float4 w = ((const float4*)wrow)[q2];
        acc0[4 * q2 + 0] += a.x * w.x; acc1[4 * q2 + 0] += a.y * w.x;
        acc0[4 * q2 + 1] += a.x * w.y; acc1[4 * q2 + 1] += a.y * w.y;
        acc0[4 * q2 + 2] += a.x * w.z; acc1[4 * q2 + 2] += a.y * w.z;
        acc0[4 * q2 + 3] += a.x * w.w; acc1[4 * q2 + 3] += a.y * w.w;
      }
      float w48 = wrow[48], w49 = wrow[49];
      acc0[48] += a.x * w48; acc1[48] += a.y * w48;
      acc0[49] += a.x * w49; acc1[49] += a.y * w49;
    }
  }

  // Reduce the 8 k-slices (binary tree over LDS), then bias+relu+store.
  __syncthreads();  // tiles dead; reuse lds as scr[4][3200]
  float* scr = lds;
  for (int half = 4; half >= 1; half >>= 1) {
    if (ks >= half && ks < 2 * half) {
      float* d = scr + (ks - half) * 3200;
#pragma unroll
      for (int jj = 0; jj < 50; ++jj) {
        d[(2 * rt) * 100 + c * 50 + jj] = acc0[jj];
        d[(2 * rt + 1) * 100 + c * 50 + jj] = acc1[jj];
      }
    }
    __syncthreads();
    if (ks < half) {
      const float* dsrc = scr + ks * 3200;
#pragma unroll
      for (int jj = 0; jj < 50; ++jj) {
        acc0[jj] += dsrc[(2 * rt) * 100 + c * 50 + jj];
        acc1[jj] += dsrc[(2 * rt + 1) * 100 + c * 50 + jj];
      }
    }
    __syncthreads();
  }
  if (ks == 0) {
#pragma unroll
    for (int jj = 0; jj < 50; ++jj) {
      int jcol = c * 50 + jj;
      float bv = be[jcol];
      h0[(size_t)(r0 + 2 * rt) * 100 + jcol] = fmaxf(acc0[jj] + bv, 0.f);
      h0[(size_t)(r0 + 2 * rt + 1) * 100 + jcol] = fmaxf(acc1[jj] + bv, 0.f);
    }
  }
}

// ---------------------------------------------------------------------------
// Tree descent: block loads NVEC consecutive 100-vectors, emits 1 vector.
// Thread (j = tid&127, s = tid>>7) caches W[j][100s..100s+99] in VGPRs.
// node out[j] = relu(b[j] + W[j][0:100].v[0:100] (s=0) + W[j][100:200].v[100:200] (s=1))
// ---------------------------------------------------------------------------
template <int NVEC>
__global__ __launch_bounds__(256, 1) void tree_levels(const float* __restrict__ in,
                                                      float* __restrict__ out,
                                                      const float* __restrict__ Wt,
                                                      const float* __restrict__ bt) {
  __shared__ __align__(16) float bufA[3200];
  __shared__ __align__(16) float bufB[1600];
  __shared__ __align__(16) float scr[1600];
  const int tid = threadIdx.x;
  const int j = tid & 127;
  const int s = tid >> 7;

  float Wreg[100];
  if (j < 100) {
    const float4* wp = (const float4*)(Wt + j * 200 + s * 100);
#pragma unroll
    for (int q = 0; q < 25; ++q) {
      float4 w = wp[q];
      Wreg[4 * q] = w.x; Wreg[4 * q + 1] = w.y;
      Wreg[4 * q + 2] = w.z; Wreg[4 * q + 3] = w.w;
    }
  }
  const float* gin = in + (size_t)blockIdx.x * NVEC * 100;
  for (int t = tid; t < NVEC * 100; t += 256) bufA[t] = gin[t];
  float bj = (j < 100) ? bt[j] : 0.f;
  __syncthreads();

  float* src = bufA;
  float* dst = bufB;
  constexpr int LEVELS = (NVEC == 32) ? 5 : 3;
#pragma unroll
  for (int l = 0; l < LEVELS; ++l) {
    const int nout = NVEC >> (l + 1);
    float p[16];
    if (j < 100) {
#pragma unroll
      for (int n = 0; n < nout; ++n) {
        const float4* v = (const float4*)(src + n * 200 + s * 100);  // broadcast
        float a0 = 0.f, a1 = 0.f, a2 = 0.f, a3 = 0.f;
#pragma unroll
        for (int q = 0; q < 25; ++q) {
          float4 x = v[q];
          a0 += Wreg[4 * q] * x.x; a1 += Wreg[4 * q + 1] * x.y;
          a2 += Wreg[4 * q + 2] * x.z; a3 += Wreg[4 * q + 3] * x.w;
        }
        p[n] = (a0 + a1) + (a2 + a3);
      }
    }
    if (s == 1 && j < 100) {
#pragma unroll
      for (int n = 0; n < nout; ++n) scr[n * 100 + j] = p[n];
    }
    __syncthreads();
    if (s == 0 && j < 100) {
#pragma unroll
      for (int n = 0; n < nout; ++n)
        dst[n * 100 + j] = fmaxf(bj + p[n] + scr[n * 100 + j], 0.f);
    }
    __syncthreads();
    float* tmp = src; src = dst; dst = tmp;
  }
  if (tid < 100) out[(size_t)blockIdx.x * 100 + tid] = src[tid];
}

// logits[cls] = bp[cls] + sum_j Wp[cls][j] * h[j]
__global__ __launch_bounds__(128) void proj_kernel(const float* __restrict__ h,
                                                   const float* __restrict__ Wp,
                                                   const float* __restrict__ bp,
                                                   float* __restrict__ out) {
  const int tid = threadIdx.x;
  const int cls = tid >> 6;
  const int l = tid & 63;
  float sum = Wp[cls * 100 + l] * h[l];
  if (l + 64 < 100) sum += Wp[cls * 100 + l + 64] * h[l + 64];
#pragma unroll
  for (int off = 32; off > 0; off >>= 1) sum += __shfl_down(sum, off, 64);
  if (l == 0) out[cls] = sum + bp[cls];
}

extern "C" void kernel_launch(void* const* d_in, const int* in_sizes, int n_in,
                              void* d_out, int out_size, void* d_ws, size_t ws_size,
                              hipStream_t stream) {
  (void)in_sizes; (void)n_in; (void)out_size; (void)ws_size;
  const float* leaf = (const float*)d_in[0];  // [8192][4096]
  const float* We = (const float*)d_in[1];    // [100][4096]
  const float* be = (const float*)d_in[2];    // [100]
  const float* W = (const float*)d_in[3];     // [100][200]
  const float* b = (const float*)d_in[4];     // [100]
  const float* Wp = (const float*)d_in[5];    // [2][100]
  const float* bp = (const float*)d_in[6];    // [2]
  float* out = (float*)d_out;                 // [2]

  float* ws = (float*)d_ws;
  float* WeT = ws;              // 4096*112        = 458752
  float* h0 = WeT + 458752;     // 8192*100        = 819200
  float* h1 = h0 + 819200;      // 256*100         = 25600
  float* h2 = h1 + 25600;       // 8*100           = 800
  float* h3 = h2 + 800;         // 100
  // total ~5.2 MB of workspace

  transpose_we<<<dim3(1792), dim3(256), 0, stream>>>(We, WeT);
  leaf_gemm<<<dim3(256), dim3(256), 0, stream>>>(leaf, WeT, be, h0);
  tree_levels<32><<<dim3(256), dim3(256), 0, stream>>>(h0, h1, W, b);  // 8192 -> 256
  tree_levels<32><<<dim3(8), dim3(256), 0, stream>>>(h1, h2, W, b);    // 256 -> 8
  tree_levels<8><<<dim3(1), dim3(256), 0, stream>>>(h2, h3, W, b);     // 8 -> 1
  proj_kernel<<<dim3(1), dim3(128), 0, stream>>>(h3, Wp, bp, out);
}

// Round 2
// 284.747 us; speedup vs baseline: 1.8974x; 1.8974x over previous
//
#include <hip/hip_runtime.h>

// Tree-RNN on MI355X.
// Leaf GEMM (8192x4096 @ 4096x100) done with fp16 hi/lo split MFMA:
//   a = ahi + alo (fp16 each, 22 mantissa bits total); A*B ~= Ahi*Bhi + Alo*Bhi + Ahi*Blo
//   error ~2^-22 relative -> logits error ~1e-5 << 5.6e-4 threshold.
// B (We) pre-converted to MFMA fragment layout (fp16 hi/lo, 2 MB, L2-resident).
// A fragments built directly from global fp32 (8 k-contiguous vals = 32 B/lane), no LDS staging.
// 256 blocks x 8 waves; block = 32 rows x 128 cols; waves split K 8-way; LDS reduce at end.
// Tree levels stay fp32 VALU (tiny), register arrays typed float4 + static unroll to avoid spills.

typedef _Float16 half_t;
typedef __attribute__((ext_vector_type(8))) _Float16 half8;
typedef __attribute__((ext_vector_type(4))) float floatx4;

// ---------------------------------------------------------------------------
// bprep: We[100][4096] fp32 -> Bf fragment layout, fp16 hi/lo.
// Fragment f = ks*16 + c*2 + h (ks=k-step of 32, c=col-tile of 16, h=hi/lo).
// Bf[f][lane][j]: element B[k = ks*32 + (lane>>4)*8 + j][n = c*16 + (lane&15)],
// B[k][n] = We[n][k] (zero-padded for n >= 100). Total 128*8*2 frags * 1 KB = 2 MB.
// ---------------------------------------------------------------------------
__global__ __launch_bounds__(256) void bprep(const float* __restrict__ We,
                                             half_t* __restrict__ Bf) {
  int t = blockIdx.x * 256 + threadIdx.x;  // 65536 threads = (ks, c, lane)
  int lane = t & 63;
  int c = (t >> 6) & 7;
  int ks = t >> 9;  // 0..127
  int q = lane >> 4, m = lane & 15;
  int n = c * 16 + m;
  int k0 = ks * 32 + q * 8;

  half8 hv, lv;
#pragma unroll
  for (int j = 0; j < 8; ++j) {
    float w = (n < 100) ? We[(size_t)n * 4096 + k0 + j] : 0.f;
    half_t hh = (half_t)w;
    hv[j] = hh;
    lv[j] = (half_t)(w - (float)hh);
  }
  size_t fhi = (size_t)(ks * 16 + c * 2 + 0) * 64 + lane;
  size_t flo = (size_t)(ks * 16 + c * 2 + 1) * 64 + lane;
  *(half8*)(Bf + fhi * 8) = hv;
  *(half8*)(Bf + flo * 8) = lv;
}

// ---------------------------------------------------------------------------
// leaf_mfma: h0[r][j] = relu(be[j] + sum_k A[r][k] * We[j][k]), compact h0 stride 100.
// Grid 256 x 512 threads (8 waves). Block: rows [32b, 32b+32), cols 0..127 (>=100 dropped).
// Wave w: K slice [w*512, (w+1)*512) = 16 k-steps of 32. No barriers until the reduce.
// ---------------------------------------------------------------------------
__global__ __launch_bounds__(512, 1) void leaf_mfma(const float* __restrict__ A,
                                                    const half8* __restrict__ Bf,
                                                    const float* __restrict__ be,
                                                    float* __restrict__ h0) {
  __shared__ float red[4 * 32 * 128];  // 64 KB reduce scratch
  const int tid = threadIdx.x;
  const int lane = tid & 63;
  const int wave = tid >> 6;
  const int q = lane >> 4, m = lane & 15;
  const int r0 = blockIdx.x * 32;

  floatx4 acc[2][8];
#pragma unroll
  for (int t = 0; t < 2; ++t)
#pragma unroll
    for (int c = 0; c < 8; ++c) acc[t][c] = (floatx4){0.f, 0.f, 0.f, 0.f};

  // A addresses: row-tile t row = r0 + t*16 + m; lane covers k = kw + s*32 + q*8 .. +7
  const float* a0 = A + (size_t)(r0 + m) * 4096 + wave * 512 + q * 8;
  const float* a1 = a0 + (size_t)16 * 4096;
  // B fragment base for this wave's first k-step (ks = wave*16): index (ks*16)*64 + lane
  const half8* bw = Bf + (size_t)wave * 256 * 64 + lane;

  floatx4 acur[4], anxt[4];
  acur[0] = *(const floatx4*)(a0);
  acur[1] = *(const floatx4*)(a0 + 4);
  acur[2] = *(const floatx4*)(a1);
  acur[3] = *(const floatx4*)(a1 + 4);

  for (int s = 0; s < 16; ++s) {
    if (s < 15) {  // prefetch next k-step's A (raw fp32) while computing this one
      const float* p0 = a0 + (s + 1) * 32;
      const float* p1 = a1 + (s + 1) * 32;
      anxt[0] = *(const floatx4*)(p0);
      anxt[1] = *(const floatx4*)(p0 + 4);
      anxt[2] = *(const floatx4*)(p1);
      anxt[3] = *(const floatx4*)(p1 + 4);
    }
    // fp32 -> fp16 hi/lo fragments
    half8 ahi[2], alo[2];
#pragma unroll
    for (int t = 0; t < 2; ++t) {
#pragma unroll
      for (int j = 0; j < 8; ++j) {
        float v = acur[2 * t + (j >> 2)][j & 3];
        half_t hh = (half_t)v;
        ahi[t][j] = hh;
        alo[t][j] = (half_t)(v - (float)hh);
      }
    }
    const half8* bs = bw + s * 1024;  // + (s*16 frags)*64
#pragma unroll
    for (int c = 0; c < 8; ++c) {
      half8 bhi = bs[c * 128];
      half8 blo = bs[c * 128 + 64];
      acc[0][c] = __builtin_amdgcn_mfma_f32_16x16x32_f16(ahi[0], bhi, acc[0][c], 0, 0, 0);
      acc[1][c] = __builtin_amdgcn_mfma_f32_16x16x32_f16(ahi[1], bhi, acc[1][c], 0, 0, 0);
      acc[0][c] = __builtin_amdgcn_mfma_f32_16x16x32_f16(alo[0], bhi, acc[0][c], 0, 0, 0);
      acc[1][c] = __builtin_amdgcn_mfma_f32_16x16x32_f16(alo[1], bhi, acc[1][c], 0, 0, 0);
      acc[0][c] = __builtin_amdgcn_mfma_f32_16x16x32_f16(ahi[0], blo, acc[0][c], 0, 0, 0);
      acc[1][c] = __builtin_amdgcn_mfma_f32_16x16x32_f16(ahi[1], blo, acc[1][c], 0, 0, 0);
    }
#pragma unroll
    for (int v = 0; v < 4; ++v) acur[v] = anxt[v];
  }

  // Reduce the 8 wave-partials over LDS (3 halving rounds, <=64 KB live).
  // C/D layout: col = lane&15 (=m), row = (lane>>4)*4 + reg (= q*4+r). [m89-verified]
#pragma unroll
  for (int hstep = 4; hstep >= 1; hstep >>= 1) {
    if (wave >= hstep && wave < 2 * hstep) {
      float* d = red + (wave - hstep) * 4096;
#pragma unroll
      for (int t = 0; t < 2; ++t)
#pragma unroll
        for (int c = 0; c < 8; ++c)
#pragma unroll
          for (int r = 0; r < 4; ++r)
            d[(t * 16 + q * 4 + r) * 128 + c * 16 + m] = acc[t][c][r];
    }
    __syncthreads();
    if (wave < hstep) {
      const float* s2 = red + wave * 4096;
#pragma unroll
      for (int t = 0; t < 2; ++t)
#pragma unroll
        for (int c = 0; c < 8; ++c)
#pragma unroll
          for (int r = 0; r < 4; ++r)
            acc[t][c][r] += s2[(t * 16 + q * 4 + r) * 128 + c * 16 + m];
    }
    __syncthreads();
  }

  if (wave == 0) {
#pragma unroll
    for (int c = 0; c < 8; ++c) {
      int col = c * 16 + m;
      if (col < 100) {
        float bias = be[col];
#pragma unroll
        for (int t = 0; t < 2; ++t)
#pragma unroll
          for (int r = 0; r < 4; ++r) {
            int row = r0 + t * 16 + q * 4 + r;
            h0[(size_t)row * 100 + col] = fmaxf(acc[t][c][r] + bias, 0.f);
          }
      }
    }
  }
}

// ---------------------------------------------------------------------------
// Tree descent: block loads NVEC consecutive 100-vectors, emits 1 vector (log2(NVEC) levels).
// Thread (j = tid&127, s = tid>>7) caches W[j][100s..100s+99] in 25 float4 regs.
// ---------------------------------------------------------------------------
template <int NVEC>
__global__ __launch_bounds__(256, 1) void tree_stage(const float* __restrict__ in,
                                                     float* __restrict__ out,
                                                     const float* __restrict__ Wt,
                                                     const float* __restrict__ bt) {
  __shared__ __align__(16) float bufA[3200];
  __shared__ __align__(16) float bufB[1600];
  __shared__ __align__(16) float scr[1600];
  const int tid = threadIdx.x;
  const int j = tid & 127;
  const int s = tid >> 7;

  floatx4 Wf[25];
  if (j < 100) {
    const floatx4* wp = (const floatx4*)(Wt + j * 200 + s * 100);
#pragma unroll
    for (int qq = 0; qq < 25; ++qq) Wf[qq] = wp[qq];
  }
  const float* gin = in + (size_t)blockIdx.x * NVEC * 100;
  for (int t = tid; t < NVEC * 100; t += 256) bufA[t] = gin[t];
  float bj = (j < 100) ? bt[j] : 0.f;
  __syncthreads();

  float* src = bufA;
  float* dst = bufB;
  constexpr int LEVELS = (NVEC == 32) ? 5 : 3;
#pragma unroll
  for (int l = 0; l < LEVELS; ++l) {
    const int nout = NVEC >> (l + 1);
    float p[16];
    if (j < 100) {
#pragma unroll
      for (int n = 0; n < nout; ++n) {
        const floatx4* v = (const floatx4*)(src + n * 200 + s * 100);  // broadcast reads
        floatx4 a = (floatx4){0.f, 0.f, 0.f, 0.f};
#pragma unroll
        for (int qq = 0; qq < 25; ++qq) {
          floatx4 x = v[qq];
          a.x += Wf[qq].x * x.x; a.y += Wf[qq].y * x.y;
          a.z += Wf[qq].z * x.z; a.w += Wf[qq].w * x.w;
        }
        p[n] = (a.x + a.y) + (a.z + a.w);
      }
    }
    if (s == 1 && j < 100) {
#pragma unroll
      for (int n = 0; n < nout; ++n) scr[n * 100 + j] = p[n];
    }
    __syncthreads();
    if (s == 0 && j < 100) {
#pragma unroll
      for (int n = 0; n < nout; ++n)
        dst[n * 100 + j] = fmaxf(bj + p[n] + scr[n * 100 + j], 0.f);
    }
    __syncthreads();
    float* tmp = src; src = dst; dst = tmp;
  }
  if (tid < 100) out[(size_t)blockIdx.x * 100 + tid] = src[tid];
}

// Tail: 8 vectors -> root vector (3 levels) -> logits, one block.
__global__ __launch_bounds__(256, 1) void tree_tail(const float* __restrict__ in,
                                                    const float* __restrict__ Wt,
                                                    const float* __restrict__ bt,
                                                    const float* __restrict__ Wp,
                                                    const float* __restrict__ bp,
                                                    float* __restrict__ logits) {
  __shared__ __align__(16) float bufA[800];
  __shared__ __align__(16) float bufB[400];
  __shared__ __align__(16) float scr[400];
  const int tid = threadIdx.x;
  const int j = tid & 127;
  const int s = tid >> 7;

  floatx4 Wf[25];
  if (j < 100) {
    const floatx4* wp = (const floatx4*)(Wt + j * 200 + s * 100);
#pragma unroll
    for (int qq = 0; qq < 25; ++qq) Wf[qq] = wp[qq];
  }
  for (int t = tid; t < 800; t += 256) bufA[t] = in[t];
  float bj = (j < 100) ? bt[j] : 0.f;
  __syncthreads();

  float* src = bufA;
  float* dst = bufB;
#pragma unroll
  for (int l = 0; l < 3; ++l) {
    const int nout = 8 >> (l + 1);
    float p[4];
    if (j < 100) {
#pragma unroll
      for (int n = 0; n < nout; ++n) {
        const floatx4* v = (const floatx4*)(src + n * 200 + s * 100);
        floatx4 a = (floatx4){0.f, 0.f, 0.f, 0.f};
#pragma unroll
        for (int qq = 0; qq < 25; ++qq) {
          floatx4 x = v[qq];
          a.x += Wf[qq].x * x.x; a.y += Wf[qq].y * x.y;
          a.z += Wf[qq].z * x.z; a.w += Wf[qq].w * x.w;
        }
        p[n] = (a.x + a.y) + (a.z + a.w);
      }
    }
    if (s == 1 && j < 100) {
#pragma unroll
      for (int n = 0; n < nout; ++n) scr[n * 100 + j] = p[n];
    }
    __syncthreads();
    if (s == 0 && j < 100) {
#pragma unroll
      for (int n = 0; n < nout; ++n)
        dst[n * 100 + j] = fmaxf(bj + p[n] + scr[n * 100 + j], 0.f);
    }
    __syncthreads();
    float* tmp = src; src = dst; dst = tmp;
  }
  // src now holds the root hidden vector (100 floats). Project to 2 logits.
  if (tid < 128) {
    int cls = tid >> 6, l = tid & 63;
    float sum = Wp[cls * 100 + l] * src[l];
    if (l + 64 < 100) sum += Wp[cls * 100 + l + 64] * src[l + 64];
#pragma unroll
    for (int off = 32; off > 0; off >>= 1) sum += __shfl_down(sum, off, 64);
    if (l == 0) logits[cls] = sum + bp[cls];
  }
}

extern "C" void kernel_launch(void* const* d_in, const int* in_sizes, int n_in,
                              void* d_out, int out_size, void* d_ws, size_t ws_size,
                              hipStream_t stream) {
  (void)in_sizes; (void)n_in; (void)out_size; (void)ws_size;
  const float* leaf = (const float*)d_in[0];  // [8192][4096]
  const float* We = (const float*)d_in[1];    // [100][4096]
  const float* be = (const float*)d_in[2];    // [100]
  const float* W = (const float*)d_in[3];     // [100][200]
  const float* b = (const float*)d_in[4];     // [100]
  const float* Wp = (const float*)d_in[5];    // [2][100]
  const float* bp = (const float*)d_in[6];    // [2]
  float* out = (float*)d_out;                 // [2]

  char* ws = (char*)d_ws;
  half_t* Bf = (half_t*)ws;                   // 2 MB (128*8*2 frags * 1 KB)
  float* h0 = (float*)(ws + 2097152);         // 8192*100 fp32 = 3.28 MB
  float* h1 = h0 + 8192 * 100;                // 256*100
  float* h2 = h1 + 256 * 100;                 // 8*100

  bprep<<<dim3(256), dim3(256), 0, stream>>>(We, Bf);
  leaf_mfma<<<dim3(256), dim3(512), 0, stream>>>(leaf, (const half8*)Bf, be, h0);
  tree_stage<32><<<dim3(256), dim3(256), 0, stream>>>(h0, h1, W, b);  // 8192 -> 256
  tree_stage<32><<<dim3(8), dim3(256), 0, stream>>>(h1, h2, W, b);    // 256 -> 8
  tree_tail<<<dim3(1), dim3(256), 0, stream>>>(h2, W, b, Wp, bp, out);
}

// Round 3
// 256.027 us; speedup vs baseline: 2.1103x; 1.1122x over previous
//
#include <hip/hip_runtime.h>

// Tree-RNN on MI355X — round 3.
// All GEMM-shaped work on MFMA via fp16 hi/lo split (a = ahi + alo, 22 mantissa bits;
// A*B ~= Ahi*Bhi + Alo*Bhi + Ahi*Blo -> ~2^-22 rel error, threshold is 5.6e-4).
//
// leaf_mfma: M=8192 K=4096 N=100(->112). 256 blocks x 8 waves, 32-row tile, BK=256.
//   A staged global->LDS via global_load_lds (1 KB contiguous per instr, 4 instrs/wave/chunk,
//   double-buffered, rows padded 1024+16 B so fragment ds_read_b128 is 2-way = free).
//   Waves k-split the chunk (32 k each). B (We) pre-fragmented fp16 hi/lo in L2 (1.8 MB).
//   B loads issued BEFORE staging instrs so the MFMA vmcnt wait leaves staging in flight.
// tree_mfma: per level, nodes = pairs[nout x 200] @ W^T -> 16xN MFMA GEMM, K padded to 224.
//   W fragments (98 KB) held in 112 VGPRs per wave; level buffers ping-pong in LDS.

typedef _Float16 half_t;
typedef __attribute__((ext_vector_type(8))) _Float16 half8;
typedef __attribute__((ext_vector_type(4))) float floatx4;

__device__ __forceinline__ void gld_lds16(const float* g, float* l) {
  __builtin_amdgcn_global_load_lds((const __attribute__((address_space(1))) void*)g,
                                   (__attribute__((address_space(3))) void*)l, 16, 0, 0);
}

__device__ __forceinline__ void cvt_hilo(const floatx4& a, const floatx4& b, half8& hi, half8& lo) {
#pragma unroll
  for (int j = 0; j < 4; ++j) {
    float v = a[j];
    half_t hh = (half_t)v;
    hi[j] = hh; lo[j] = (half_t)(v - (float)hh);
  }
#pragma unroll
  for (int j = 0; j < 4; ++j) {
    float v = b[j];
    half_t hh = (half_t)v;
    hi[4 + j] = hh; lo[4 + j] = (half_t)(v - (float)hh);
  }
}

// ---------------------------------------------------------------------------
// bprep: We[100][4096] -> Bf fragments (fp16 hi/lo), frag = ks*14 + c*2 + h.
// Fragment element: B[k = ks*32 + (lane>>4)*8 + j][n = c*16 + (lane&15)] = We[n][k].
// Coalesced reads: consecutive threads = consecutive k. (Tile-6 lanes with n>=100
// are never written -> 0xAA poison -> finite fp16 garbage in discarded cols. Safe.)
// ---------------------------------------------------------------------------
__global__ __launch_bounds__(256) void bprep(const float* __restrict__ We,
                                             half_t* __restrict__ Bf) {
  int t = blockIdx.x * 256 + threadIdx.x;  // 100 n x 512 kp
  if (t >= 51200) return;
  int n = t >> 9;
  int kp = t & 511;
  int k0 = kp * 8;
  int ks = k0 >> 5;
  int q = (k0 >> 3) & 3;
  int c = n >> 4, m = n & 15;
  int lane = q * 16 + m;

  const float* src = We + (size_t)n * 4096 + k0;
  half8 hv, lv;
#pragma unroll
  for (int j = 0; j < 8; ++j) {
    float w = src[j];
    half_t hh = (half_t)w;
    hv[j] = hh; lv[j] = (half_t)(w - (float)hh);
  }
  size_t base = (size_t)(ks * 14 + c * 2) * 64 + lane;
  *(half8*)(Bf + base * 8) = hv;
  *(half8*)(Bf + (base + 64) * 8) = lv;
}

// ---------------------------------------------------------------------------
// wprep: W[100][200] -> Wf fragments for the tree GEMM (K padded 200->224, N->112).
// frag = ks*14 + tile*2 + h, ks 0..6, tile 0..6. Zero-filled out of range.
// ---------------------------------------------------------------------------
__global__ __launch_bounds__(64) void wprep(const float* __restrict__ W,
                                            half_t* __restrict__ Wf) {
  int ks = blockIdx.x / 7, tt = blockIdx.x % 7;
  int lane = threadIdx.x;
  int q = lane >> 4, n = lane & 15;
  int col = tt * 16 + n;
  int kb = ks * 32 + q * 8;
  half8 hv, lv;
#pragma unroll
  for (int j = 0; j < 8; ++j) {
    int k = kb + j;
    float w = (col < 100 && k < 200) ? W[(size_t)col * 200 + k] : 0.f;
    half_t hh = (half_t)w;
    hv[j] = hh; lv[j] = (half_t)(w - (float)hh);
  }
  size_t base = (size_t)(ks * 14 + tt * 2) * 64 + lane;
  *(half8*)(Wf + base * 8) = hv;
  *(half8*)(Wf + (base + 64) * 8) = lv;
}

// ---------------------------------------------------------------------------
// leaf_mfma: h0[r][j] = relu(be[j] + sum_k A[r][k]*We[j][k]).
// 256 blocks x 512 thr. Rows [32b,32b+32). 16 chunks of BK=256; wave w owns k-sub w*32.
// ---------------------------------------------------------------------------
__global__ __launch_bounds__(512, 1) void leaf_mfma(const float* __restrict__ A,
                                                    const half8* __restrict__ Bf,
                                                    const float* __restrict__ be,
                                                    float* __restrict__ h0) {
  __shared__ __align__(16) float lds[2 * 32 * 260];  // 66560 B; row stride 260 floats
  const int tid = threadIdx.x;
  const int lane = tid & 63;
  const int wave = tid >> 6;
  const int q = lane >> 4, m = lane & 15;
  const int r0 = blockIdx.x * 32;

  floatx4 acc[2][7];
#pragma unroll
  for (int t = 0; t < 2; ++t)
#pragma unroll
    for (int c = 0; c < 7; ++c) acc[t][c] = (floatx4){0.f, 0.f, 0.f, 0.f};

  {  // stage chunk 0
    const float* g = A + (size_t)(r0 + wave * 4) * 4096 + lane * 4;
    float* d = lds + (wave * 4) * 260 + lane * 4;
#pragma unroll
    for (int i = 0; i < 4; ++i) gld_lds16(g + (size_t)i * 4096, d + i * 260);
  }
  __syncthreads();

  for (int t = 0; t < 16; ++t) {
    float* cur = lds + (t & 1) * 8320;
    float* nxt = lds + ((t + 1) & 1) * 8320;

    // B fragment loads FIRST (older in vmcnt queue than staging -> MFMA wait
    // for B leaves the staging loads outstanding).
    const int ksg = t * 8 + wave;
    const half8* bb = Bf + (size_t)(ksg * 14) * 64 + lane;
    half8 bhi[7], blo[7];
#pragma unroll
    for (int c = 0; c < 7; ++c) { bhi[c] = bb[c * 128]; blo[c] = bb[c * 128 + 64]; }

    if (t < 15) {  // stage next chunk (async into LDS)
      const float* g = A + (size_t)(r0 + wave * 4) * 4096 + (t + 1) * 256 + lane * 4;
      float* d = nxt + (wave * 4) * 260 + lane * 4;
#pragma unroll
      for (int i = 0; i < 4; ++i) gld_lds16(g + (size_t)i * 4096, d + i * 260);
    }

    // A fragments from LDS (2-way bank aliasing = free)
    const float* ap = cur + m * 260 + wave * 32 + q * 8;
    floatx4 a0 = *(const floatx4*)ap;
    floatx4 a1 = *(const floatx4*)(ap + 4);
    floatx4 a2 = *(const floatx4*)(ap + 16 * 260);
    floatx4 a3 = *(const floatx4*)(ap + 16 * 260 + 4);
    half8 ahi[2], alo[2];
    cvt_hilo(a0, a1, ahi[0], alo[0]);
    cvt_hilo(a2, a3, ahi[1], alo[1]);

#pragma unroll
    for (int c = 0; c < 7; ++c) {
      acc[0][c] = __builtin_amdgcn_mfma_f32_16x16x32_f16(ahi[0], bhi[c], acc[0][c], 0, 0, 0);
      acc[1][c] = __builtin_amdgcn_mfma_f32_16x16x32_f16(ahi[1], bhi[c], acc[1][c], 0, 0, 0);
      acc[0][c] = __builtin_amdgcn_mfma_f32_16x16x32_f16(alo[0], bhi[c], acc[0][c], 0, 0, 0);
      acc[1][c] = __builtin_amdgcn_mfma_f32_16x16x32_f16(alo[1], bhi[c], acc[1][c], 0, 0, 0);
      acc[0][c] = __builtin_amdgcn_mfma_f32_16x16x32_f16(ahi[0], blo[c], acc[0][c], 0, 0, 0);
      acc[1][c] = __builtin_amdgcn_mfma_f32_16x16x32_f16(ahi[1], blo[c], acc[1][c], 0, 0, 0);
    }
    __syncthreads();  // staging for t+1 complete (vmcnt(0) at barrier) + cur reads done
  }

  // 8-way k-split reduce over LDS (overlay; 4*32*112*4 = 57344 <= 66560 B).
  float* red = lds;
#pragma unroll
  for (int h = 4; h >= 1; h >>= 1) {
    if (wave >= h && wave < 2 * h) {
      float* d = red + (wave - h) * 3584;
#pragma unroll
      for (int t = 0; t < 2; ++t)
#pragma unroll
        for (int c = 0; c < 7; ++c)
#pragma unroll
          for (int r = 0; r < 4; ++r)
            d[(t * 16 + q * 4 + r) * 112 + c * 16 + m] = acc[t][c][r];
    }
    __syncthreads();
    if (wave < h) {
      const float* s = red + wave * 3584;
#pragma unroll
      for (int t = 0; t < 2; ++t)
#pragma unroll
        for (int c = 0; c < 7; ++c)
#pragma unroll
          for (int r = 0; r < 4; ++r)
            acc[t][c][r] += s[(t * 16 + q * 4 + r) * 112 + c * 16 + m];
    }
    __syncthreads();
  }

  if (wave == 0) {
#pragma unroll
    for (int c = 0; c < 7; ++c) {
      int col = c * 16 + m;
      if (col < 100) {
        float bv = be[col];
#pragma unroll
        for (int t = 0; t < 2; ++t)
#pragma unroll
          for (int r = 0; r < 4; ++r) {
            int row = r0 + t * 16 + q * 4 + r;
            h0[(size_t)row * 100 + col] = fmaxf(acc[t][c][r] + bv, 0.f);
          }
      }
    }
  }
}

// ---------------------------------------------------------------------------
// tree_mfma: block takes NVEC consecutive 100-vectors -> log2(NVEC) levels -> 1 vector.
// Level GEMM: out[row][col] = relu(b[col] + sum_k pair[row][k] * W[col][k]), K=200->224.
// 4 waves; wave w covers col-tiles {2w, min(2w+1,6)}; W fragments in VGPRs.
// Pair buffers [16][228] ping-pong in LDS (stride 228 -> 2-way bank aliasing = free).
// ---------------------------------------------------------------------------
template <int NVEC>
__global__ __launch_bounds__(256, 1) void tree_mfma(const float* __restrict__ in,
                                                    float* __restrict__ out,
                                                    const half8* __restrict__ Wf,
                                                    const float* __restrict__ bt) {
  __shared__ __align__(16) float bufA[16 * 228];
  __shared__ __align__(16) float bufB[16 * 228];
  const int tid = threadIdx.x;
  const int lane = tid & 63;
  const int wave = tid >> 6;
  const int q = lane >> 4, m = lane & 15;
  const int t0 = 2 * wave;
  const int t1 = (2 * wave + 1 > 6) ? 6 : 2 * wave + 1;

  half8 wh0[7], wl0[7], wh1[7], wl1[7];
#pragma unroll
  for (int ks = 0; ks < 7; ++ks) {
    wh0[ks] = Wf[(size_t)(ks * 14 + t0 * 2) * 64 + lane];
    wl0[ks] = Wf[(size_t)(ks * 14 + t0 * 2 + 1) * 64 + lane];
    wh1[ks] = Wf[(size_t)(ks * 14 + t1 * 2) * 64 + lane];
    wl1[ks] = Wf[(size_t)(ks * 14 + t1 * 2 + 1) * 64 + lane];
  }
  const int c0 = t0 * 16 + m;
  const int c1 = t1 * 16 + m;
  const float b0 = (c0 < 100) ? bt[c0] : 0.f;
  const float b1 = (c1 < 100) ? bt[c1] : 0.f;

  for (int i = tid; i < 16 * 228; i += 256) { bufA[i] = 0.f; bufB[i] = 0.f; }
  __syncthreads();
  const float* gin = in + (size_t)blockIdx.x * NVEC * 100;
  for (int i = tid; i < NVEC * 100; i += 256) {
    int v = i / 100, j = i - v * 100;
    bufA[(v >> 1) * 228 + (v & 1) * 100 + j] = gin[i];
  }
  __syncthreads();

  float* src = bufA;
  float* dst = bufB;
  constexpr int L = (NVEC == 32) ? 5 : 3;
#pragma unroll
  for (int l = 0; l < L; ++l) {
    const int nout = NVEC >> (l + 1);
    floatx4 acc0 = (floatx4){0.f, 0.f, 0.f, 0.f};
    floatx4 acc1 = (floatx4){0.f, 0.f, 0.f, 0.f};
#pragma unroll
    for (int ks = 0; ks < 7; ++ks) {
      const float* ap = src + m * 228 + ks * 32 + q * 8;  // row m = output node (stale if >= nout, discarded)
      floatx4 x0 = *(const floatx4*)ap;
      floatx4 x1 = *(const floatx4*)(ap + 4);
      half8 ah, al;
      cvt_hilo(x0, x1, ah, al);
      acc0 = __builtin_amdgcn_mfma_f32_16x16x32_f16(ah, wh0[ks], acc0, 0, 0, 0);
      acc1 = __builtin_amdgcn_mfma_f32_16x16x32_f16(ah, wh1[ks], acc1, 0, 0, 0);
      acc0 = __builtin_amdgcn_mfma_f32_16x16x32_f16(al, wh0[ks], acc0, 0, 0, 0);
      acc1 = __builtin_amdgcn_mfma_f32_16x16x32_f16(al, wh1[ks], acc1, 0, 0, 0);
      acc0 = __builtin_amdgcn_mfma_f32_16x16x32_f16(ah, wl0[ks], acc0, 0, 0, 0);
      acc1 = __builtin_amdgcn_mfma_f32_16x16x32_f16(ah, wl1[ks], acc1, 0, 0, 0);
    }
    // write outputs into dst as next level's pair rows
#pragma unroll
    for (int r = 0; r < 4; ++r) {
      int rowR = q * 4 + r;
      if (rowR < nout) {
        if (c0 < 100)
          dst[(rowR >> 1) * 228 + (rowR & 1) * 100 + c0] = fmaxf(acc0[r] + b0, 0.f);
        if (t1 != t0 && c1 < 100)
          dst[(rowR >> 1) * 228 + (rowR & 1) * 100 + c1] = fmaxf(acc1[r] + b1, 0.f);
      }
    }
    __syncthreads();
    float* tmp = src; src = dst; dst = tmp;
  }
  // result vector = node 0 of final level, at src[0..99]
  if (tid < 100) out[(size_t)blockIdx.x * 100 + tid] = src[tid];
}

// logits[cls] = bp[cls] + sum_j Wp[cls][j] * h[j]
__global__ __launch_bounds__(128) void proj_kernel(const float* __restrict__ h,
                                                   const float* __restrict__ Wp,
                                                   const float* __restrict__ bp,
                                                   float* __restrict__ out) {
  const int tid = threadIdx.x;
  const int cls = tid >> 6;
  const int l = tid & 63;
  float sum = Wp[cls * 100 + l] * h[l];
  if (l + 64 < 100) sum += Wp[cls * 100 + l + 64] * h[l + 64];
#pragma unroll
  for (int off = 32; off > 0; off >>= 1) sum += __shfl_down(sum, off, 64);
  if (l == 0) out[cls] = sum + bp[cls];
}

extern "C" void kernel_launch(void* const* d_in, const int* in_sizes, int n_in,
                              void* d_out, int out_size, void* d_ws, size_t ws_size,
                              hipStream_t stream) {
  (void)in_sizes; (void)n_in; (void)out_size; (void)ws_size;
  const float* leaf = (const float*)d_in[0];  // [8192][4096]
  const float* We = (const float*)d_in[1];    // [100][4096]
  const float* be = (const float*)d_in[2];    // [100]
  const float* W = (const float*)d_in[3];     // [100][200]
  const float* b = (const float*)d_in[4];     // [100]
  const float* Wp = (const float*)d_in[5];    // [2][100]
  const float* bp = (const float*)d_in[6];    // [2]
  float* out = (float*)d_out;                 // [2]

  char* ws = (char*)d_ws;
  half_t* Bf = (half_t*)ws;                        // 1792 frags * 1 KB = 1,835,008 B
  half_t* Wfr = (half_t*)(ws + 1835008);           // 98 frags * 1 KB = 100,352 B
  float* h0 = (float*)(ws + 1935360);              // 8192*100*4 = 3,276,800 B
  float* h1 = (float*)(ws + 5212160);              // 256*100*4
  float* h2 = (float*)(ws + 5314560);              // 8*100*4
  float* h3 = (float*)(ws + 5317760);              // 100*4

  bprep<<<dim3(200), dim3(256), 0, stream>>>(We, Bf);
  wprep<<<dim3(49), dim3(64), 0, stream>>>(W, Wfr);
  leaf_mfma<<<dim3(256), dim3(512), 0, stream>>>(leaf, (const half8*)Bf, be, h0);
  tree_mfma<32><<<dim3(256), dim3(256), 0, stream>>>(h0, h1, (const half8*)Wfr, b);  // 8192->256
  tree_mfma<32><<<dim3(8), dim3(256), 0, stream>>>(h1, h2, (const half8*)Wfr, b);    // 256->8
  tree_mfma<8><<<dim3(1), dim3(256), 0, stream>>>(h2, h3, (const half8*)Wfr, b);     // 8->1
  proj_kernel<<<dim3(1), dim3(128), 0, stream>>>(h3, Wp, bp, out);
}

// Round 4
// 249.793 us; speedup vs baseline: 2.1629x; 1.0250x over previous
//
#include <hip/hip_runtime.h>

// Tree-RNN on MI355X — round 4.
// All GEMM work on MFMA via fp16 hi/lo split (a = ahi+alo; A*B ~= Ahi*Bhi+Alo*Bhi+Ahi*Blo,
// ~2^-22 rel err vs 5.6e-4 threshold).
//
// R4 change: leaf K-loop restructured AITER-style — raw s_barrier + manual s_waitcnt vmcnt(N)
// + TRIPLE-buffered LDS staging, so next-chunk global_load_lds stays in flight across the
// barrier (R3's __syncthreads forced vmcnt(0) each chunk = full drain = ~30 us; fix -> ~21 us
// HBM-floor). Projection fused into the final tree kernel.

typedef _Float16 half_t;
typedef __attribute__((ext_vector_type(8))) _Float16 half8;
typedef __attribute__((ext_vector_type(4))) float floatx4;

#define VMCNT_4 0xF74  // s_waitcnt vmcnt(4), expcnt/lgkmcnt unconstrained
#define VMCNT_0 0xF70  // s_waitcnt vmcnt(0)

__device__ __forceinline__ void gld_lds16(const float* g, float* l) {
  __builtin_amdgcn_global_load_lds((const __attribute__((address_space(1))) void*)g,
                                   (__attribute__((address_space(3))) void*)l, 16, 0, 0);
}

__device__ __forceinline__ void cvt_hilo(const floatx4& a, const floatx4& b, half8& hi, half8& lo) {
#pragma unroll
  for (int j = 0; j < 4; ++j) {
    float v = a[j];
    half_t hh = (half_t)v;
    hi[j] = hh; lo[j] = (half_t)(v - (float)hh);
  }
#pragma unroll
  for (int j = 0; j < 4; ++j) {
    float v = b[j];
    half_t hh = (half_t)v;
    hi[4 + j] = hh; lo[4 + j] = (half_t)(v - (float)hh);
  }
}

// ---------------------------------------------------------------------------
// bprep: We[100][4096] -> Bf fragments (fp16 hi/lo), frag = ks*14 + c*2 + h.
// Element: B[k = ks*32 + (lane>>4)*8 + j][n = c*16 + (lane&15)] = We[n][k].
// ---------------------------------------------------------------------------
__global__ __launch_bounds__(256) void bprep(const float* __restrict__ We,
                                             half_t* __restrict__ Bf) {
  int t = blockIdx.x * 256 + threadIdx.x;  // 100 n x 512 kp
  if (t >= 51200) return;
  int n = t >> 9;
  int kp = t & 511;
  int k0 = kp * 8;
  int ks = k0 >> 5;
  int q = (k0 >> 3) & 3;
  int c = n >> 4, m = n & 15;
  int lane = q * 16 + m;

  const float* src = We + (size_t)n * 4096 + k0;
  half8 hv, lv;
#pragma unroll
  for (int j = 0; j < 8; ++j) {
    float w = src[j];
    half_t hh = (half_t)w;
    hv[j] = hh; lv[j] = (half_t)(w - (float)hh);
  }
  size_t base = (size_t)(ks * 14 + c * 2) * 64 + lane;
  *(half8*)(Bf + base * 8) = hv;
  *(half8*)(Bf + (base + 64) * 8) = lv;
}

// wprep: W[100][200] -> fragments, K padded 200->224, N->112. frag = ks*14 + tile*2 + h.
__global__ __launch_bounds__(64) void wprep(const float* __restrict__ W,
                                            half_t* __restrict__ Wf) {
  int ks = blockIdx.x / 7, tt = blockIdx.x % 7;
  int lane = threadIdx.x;
  int q = lane >> 4, n = lane & 15;
  int col = tt * 16 + n;
  int kb = ks * 32 + q * 8;
  half8 hv, lv;
#pragma unroll
  for (int j = 0; j < 8; ++j) {
    int k = kb + j;
    float w = (col < 100 && k < 200) ? W[(size_t)col * 200 + k] : 0.f;
    half_t hh = (half_t)w;
    hv[j] = hh; lv[j] = (half_t)(w - (float)hh);
  }
  size_t base = (size_t)(ks * 14 + tt * 2) * 64 + lane;
  *(half8*)(Wf + base * 8) = hv;
  *(half8*)(Wf + (base + 64) * 8) = lv;
}

// ---------------------------------------------------------------------------
// leaf_mfma: h0[r][j] = relu(be[j] + sum_k A[r][k]*We[j][k]).
// 256 blocks x 512 thr (8 waves), rows [32b,32b+32), 16 chunks of BK=256, wave w owns
// k-substep w*32 of each chunk. Triple-buffered staging, raw s_barrier + manual vmcnt.
// ---------------------------------------------------------------------------
__global__ __launch_bounds__(512, 1) void leaf_mfma(const float* __restrict__ A,
                                                    const half8* __restrict__ Bf,
                                                    const float* __restrict__ be,
                                                    float* __restrict__ h0) {
  __shared__ __align__(16) float lds[3 * 8320];  // 3 bufs x 32 rows x 260 fl = 99,840 B
  const int tid = threadIdx.x;
  const int lane = tid & 63;
  const int wave = tid >> 6;
  const int q = lane >> 4, m = lane & 15;
  const int r0 = blockIdx.x * 32;

  floatx4 acc[2][7];
#pragma unroll
  for (int t = 0; t < 2; ++t)
#pragma unroll
    for (int c = 0; c < 7; ++c) acc[t][c] = (floatx4){0.f, 0.f, 0.f, 0.f};

  // each wave stages 4 rows x 1 KB per chunk (contiguous per row; LDS dest is
  // wave-uniform base + lane*16, matching the lane*4-float layout)
  const float* gbase = A + (size_t)(r0 + wave * 4) * 4096 + lane * 4;
  const int ldso = (wave * 4) * 260 + lane * 4;

  // prologue: chunks 0 and 1 in flight; drain chunk 0 only.
  {
    const float* g0 = gbase;
    const float* g1 = gbase + 256;
#pragma unroll
    for (int i = 0; i < 4; ++i) gld_lds16(g0 + (size_t)i * 4096, lds + ldso + i * 260);
#pragma unroll
    for (int i = 0; i < 4; ++i) gld_lds16(g1 + (size_t)i * 4096, lds + 8320 + ldso + i * 260);
  }
  __builtin_amdgcn_s_waitcnt(VMCNT_4);  // chunk0 done, chunk1 still in flight
  __builtin_amdgcn_s_barrier();

  int bc = 0;  // current buffer index = t % 3
  for (int t = 0; t < 16; ++t) {
    // B fragment loads first (oldest in queue -> compiler's B-wait = vmcnt(4),
    // which drains stage(t+1) but keeps stage(t+2) in flight).
    const int ksg = t * 8 + wave;
    const half8* bb = Bf + (size_t)(ksg * 14) * 64 + lane;
    half8 bhi[7], blo[7];
#pragma unroll
    for (int c = 0; c < 7; ++c) { bhi[c] = bb[c * 128]; blo[c] = bb[c * 128 + 64]; }

    if (t < 14) {  // stage chunk t+2 into buffer (t+2)%3
      int bn = bc + 2; if (bn >= 3) bn -= 3;
      const float* g = gbase + (t + 2) * 256;
      float* d = lds + bn * 8320 + ldso;
#pragma unroll
      for (int i = 0; i < 4; ++i) gld_lds16(g + (size_t)i * 4096, d + i * 260);
    }

    // A fragments from LDS buffer t%3
    const float* ap = lds + bc * 8320 + m * 260 + wave * 32 + q * 8;
    floatx4 a0 = *(const floatx4*)ap;
    floatx4 a1 = *(const floatx4*)(ap + 4);
    floatx4 a2 = *(const floatx4*)(ap + 16 * 260);
    floatx4 a3 = *(const floatx4*)(ap + 16 * 260 + 4);
    half8 ahi[2], alo[2];
    cvt_hilo(a0, a1, ahi[0], alo[0]);
    cvt_hilo(a2, a3, ahi[1], alo[1]);

#pragma unroll
    for (int c = 0; c < 7; ++c) {
      acc[0][c] = __builtin_amdgcn_mfma_f32_16x16x32_f16(ahi[0], bhi[c], acc[0][c], 0, 0, 0);
      acc[1][c] = __builtin_amdgcn_mfma_f32_16x16x32_f16(ahi[1], bhi[c], acc[1][c], 0, 0, 0);
      acc[0][c] = __builtin_amdgcn_mfma_f32_16x16x32_f16(alo[0], bhi[c], acc[0][c], 0, 0, 0);
      acc[1][c] = __builtin_amdgcn_mfma_f32_16x16x32_f16(alo[1], bhi[c], acc[1][c], 0, 0, 0);
      acc[0][c] = __builtin_amdgcn_mfma_f32_16x16x32_f16(ahi[0], blo[c], acc[0][c], 0, 0, 0);
      acc[1][c] = __builtin_amdgcn_mfma_f32_16x16x32_f16(ahi[1], blo[c], acc[1][c], 0, 0, 0);
    }

    // Pre-barrier: ensure stage(t+1) complete (keep stage(t+2) in flight) -> raw barrier.
    if (t < 14) __builtin_amdgcn_s_waitcnt(VMCNT_4);
    else        __builtin_amdgcn_s_waitcnt(VMCNT_0);
    __builtin_amdgcn_s_barrier();

    bc += 1; if (bc >= 3) bc -= 3;
  }

  // 8-way k-split reduce over LDS (overlay: 4*32*112*4 = 57,344 B <= 99,840).
  float* red = lds;
#pragma unroll
  for (int h = 4; h >= 1; h >>= 1) {
    if (wave >= h && wave < 2 * h) {
      float* d = red + (wave - h) * 3584;
#pragma unroll
      for (int t = 0; t < 2; ++t)
#pragma unroll
        for (int c = 0; c < 7; ++c)
#pragma unroll
          for (int r = 0; r < 4; ++r)
            d[(t * 16 + q * 4 + r) * 112 + c * 16 + m] = acc[t][c][r];
    }
    __syncthreads();
    if (wave < h) {
      const float* s = red + wave * 3584;
#pragma unroll
      for (int t = 0; t < 2; ++t)
#pragma unroll
        for (int c = 0; c < 7; ++c)
#pragma unroll
          for (int r = 0; r < 4; ++r)
            acc[t][c][r] += s[(t * 16 + q * 4 + r) * 112 + c * 16 + m];
    }
    __syncthreads();
  }

  if (wave == 0) {
#pragma unroll
    for (int c = 0; c < 7; ++c) {
      int col = c * 16 + m;
      if (col < 100) {
        float bv = be[col];
#pragma unroll
        for (int t = 0; t < 2; ++t)
#pragma unroll
          for (int r = 0; r < 4; ++r) {
            int row = r0 + t * 16 + q * 4 + r;
            h0[(size_t)row * 100 + col] = fmaxf(acc[t][c][r] + bv, 0.f);
          }
      }
    }
  }
}

// ---------------------------------------------------------------------------
// tree_mfma: block takes NVEC consecutive 100-vectors -> log2(NVEC) levels -> 1 vector.
// Level GEMM: out[row][col] = relu(b[col] + sum_k pair[row][k]*W[col][k]), K=200->224.
// 4 waves; wave w covers col-tiles {2w, min(2w+1,6)}; W fragments in VGPRs.
// PROJ: final kernel also computes the 2 logits from the root vector.
// ---------------------------------------------------------------------------
template <int NVEC, bool PROJ>
__global__ __launch_bounds__(256, 1) void tree_mfma(const float* __restrict__ in,
                                                    float* __restrict__ out,
                                                    const half8* __restrict__ Wf,
                                                    const float* __restrict__ bt,
                                                    const float* __restrict__ Wp,
                                                    const float* __restrict__ bp) {
  __shared__ __align__(16) float bufA[16 * 228];
  __shared__ __align__(16) float bufB[16 * 228];
  const int tid = threadIdx.x;
  const int lane = tid & 63;
  const int wave = tid >> 6;
  const int q = lane >> 4, m = lane & 15;
  const int t0 = 2 * wave;
  const int t1 = (2 * wave + 1 > 6) ? 6 : 2 * wave + 1;

  half8 wh0[7], wl0[7], wh1[7], wl1[7];
#pragma unroll
  for (int ks = 0; ks < 7; ++ks) {
    wh0[ks] = Wf[(size_t)(ks * 14 + t0 * 2) * 64 + lane];
    wl0[ks] = Wf[(size_t)(ks * 14 + t0 * 2 + 1) * 64 + lane];
    wh1[ks] = Wf[(size_t)(ks * 14 + t1 * 2) * 64 + lane];
    wl1[ks] = Wf[(size_t)(ks * 14 + t1 * 2 + 1) * 64 + lane];
  }
  const int c0 = t0 * 16 + m;
  const int c1 = t1 * 16 + m;
  const float b0 = (c0 < 100) ? bt[c0] : 0.f;
  const float b1 = (c1 < 100) ? bt[c1] : 0.f;

  for (int i = tid; i < 16 * 228; i += 256) { bufA[i] = 0.f; bufB[i] = 0.f; }
  __syncthreads();
  const float* gin = in + (size_t)blockIdx.x * NVEC * 100;
  for (int i = tid; i < NVEC * 100; i += 256) {
    int v = i / 100, j = i - v * 100;
    bufA[(v >> 1) * 228 + (v & 1) * 100 + j] = gin[i];
  }
  __syncthreads();

  float* src = bufA;
  float* dst = bufB;
  constexpr int L = (NVEC == 32) ? 5 : 3;
#pragma unroll
  for (int l = 0; l < L; ++l) {
    const int nout = NVEC >> (l + 1);
    floatx4 acc0 = (floatx4){0.f, 0.f, 0.f, 0.f};
    floatx4 acc1 = (floatx4){0.f, 0.f, 0.f, 0.f};
#pragma unroll
    for (int ks = 0; ks < 7; ++ks) {
      const float* ap = src + m * 228 + ks * 32 + q * 8;
      floatx4 x0 = *(const floatx4*)ap;
      floatx4 x1 = *(const floatx4*)(ap + 4);
      half8 ah, al;
      cvt_hilo(x0, x1, ah, al);
      acc0 = __builtin_amdgcn_mfma_f32_16x16x32_f16(ah, wh0[ks], acc0, 0, 0, 0);
      acc1 = __builtin_amdgcn_mfma_f32_16x16x32_f16(ah, wh1[ks], acc1, 0, 0, 0);
      acc0 = __builtin_amdgcn_mfma_f32_16x16x32_f16(al, wh0[ks], acc0, 0, 0, 0);
      acc1 = __builtin_amdgcn_mfma_f32_16x16x32_f16(al, wh1[ks], acc1, 0, 0, 0);
      acc0 = __builtin_amdgcn_mfma_f32_16x16x32_f16(ah, wl0[ks], acc0, 0, 0, 0);
      acc1 = __builtin_amdgcn_mfma_f32_16x16x32_f16(ah, wl1[ks], acc1, 0, 0, 0);
    }
#pragma unroll
    for (int r = 0; r < 4; ++r) {
      int rowR = q * 4 + r;
      if (rowR < nout) {
        if (c0 < 100)
          dst[(rowR >> 1) * 228 + (rowR & 1) * 100 + c0] = fmaxf(acc0[r] + b0, 0.f);
        if (t1 != t0 && c1 < 100)
          dst[(rowR >> 1) * 228 + (rowR & 1) * 100 + c1] = fmaxf(acc1[r] + b1, 0.f);
      }
    }
    __syncthreads();
    float* tmp = src; src = dst; dst = tmp;
  }
  if (PROJ) {
    // root hidden vector = src[0..99]; logits[cls] = bp[cls] + sum_j Wp[cls][j]*src[j]
    if (tid < 128) {
      int cls = tid >> 6, l = tid & 63;
      float sum = Wp[cls * 100 + l] * src[l];
      if (l + 64 < 100) sum += Wp[cls * 100 + l + 64] * src[l + 64];
#pragma unroll
      for (int off = 32; off > 0; off >>= 1) sum += __shfl_down(sum, off, 64);
      if (l == 0) out[cls] = sum + bp[cls];
    }
  } else {
    if (tid < 100) out[(size_t)blockIdx.x * 100 + tid] = src[tid];
  }
}

extern "C" void kernel_launch(void* const* d_in, const int* in_sizes, int n_in,
                              void* d_out, int out_size, void* d_ws, size_t ws_size,
                              hipStream_t stream) {
  (void)in_sizes; (void)n_in; (void)out_size; (void)ws_size;
  const float* leaf = (const float*)d_in[0];  // [8192][4096]
  const float* We = (const float*)d_in[1];    // [100][4096]
  const float* be = (const float*)d_in[2];    // [100]
  const float* W = (const float*)d_in[3];     // [100][200]
  const float* b = (const float*)d_in[4];     // [100]
  const float* Wp = (const float*)d_in[5];    // [2][100]
  const float* bp = (const float*)d_in[6];    // [2]
  float* out = (float*)d_out;                 // [2]

  char* ws = (char*)d_ws;
  half_t* Bf = (half_t*)ws;                        // 1792 frags * 1 KB
  half_t* Wfr = (half_t*)(ws + 1835008);           // 98 frags * 1 KB
  float* h0 = (float*)(ws + 1935360);              // 8192*100 fp32
  float* h1 = (float*)(ws + 5212160);              // 256*100
  float* h2 = (float*)(ws + 5314560);              // 8*100

  bprep<<<dim3(200), dim3(256), 0, stream>>>(We, Bf);
  wprep<<<dim3(49), dim3(64), 0, stream>>>(W, Wfr);
  leaf_mfma<<<dim3(256), dim3(512), 0, stream>>>(leaf, (const half8*)Bf, be, h0);
  tree_mfma<32, false><<<dim3(256), dim3(256), 0, stream>>>(h0, h1, (const half8*)Wfr, b, nullptr, nullptr);
  tree_mfma<32, false><<<dim3(8), dim3(256), 0, stream>>>(h1, h2, (const half8*)Wfr, b, nullptr, nullptr);
  tree_mfma<8, true><<<dim3(1), dim3(256), 0, stream>>>(h2, out, (const half8*)Wfr, b, Wp, bp);
}

// Round 5
// 249.148 us; speedup vs baseline: 2.1685x; 1.0026x over previous
//
#include <hip/hip_runtime.h>

// Tree-RNN on MI355X — round 5.
// All GEMM work on MFMA via fp16 hi/lo split (a = ahi+alo; A*B ~= Ahi*Bhi+Alo*Bhi+Ahi*Blo,
// ~2^-22 rel err vs 5.6e-4 threshold).
//
// R5: leaf rebuilt for 2 blocks/CU TLP (m114 overlap) instead of manual-vmcnt games (m131:
// compiler defeats them). 512 blocks = 256 row-tiles x 2 K-halves; waves N-split (no k-reduce);
// all B frags for a chunk loaded up-front (oldest in vmcnt queue, pinned by sched_barrier) so
// B-waits never drain the async staging queue. Two partial h0 buffers; tree stage 1 sums them
// and applies bias+relu at load. bprep+wprep merged. 5 launches.

typedef _Float16 half_t;
typedef __attribute__((ext_vector_type(8))) _Float16 half8;
typedef __attribute__((ext_vector_type(4))) float floatx4;

#define H0ROWS ((size_t)8192 * 112)

__device__ __forceinline__ void gld_lds16(const float* g, float* l) {
  __builtin_amdgcn_global_load_lds((const __attribute__((address_space(1))) void*)g,
                                   (__attribute__((address_space(3))) void*)l, 16, 0, 0);
}

__device__ __forceinline__ void cvt_hilo(const floatx4& a, const floatx4& b, half8& hi, half8& lo) {
#pragma unroll
  for (int j = 0; j < 4; ++j) {
    float v = a[j];
    half_t hh = (half_t)v;
    hi[j] = hh; lo[j] = (half_t)(v - (float)hh);
  }
#pragma unroll
  for (int j = 0; j < 4; ++j) {
    float v = b[j];
    half_t hh = (half_t)v;
    hi[4 + j] = hh; lo[4 + j] = (half_t)(v - (float)hh);
  }
}

// ---------------------------------------------------------------------------
// prep: blocks 0..199 convert We[100][4096] -> Bf fragments (frag = ks*14 + c*2 + h,
// element B[k=ks*32+(lane>>4)*8+j][n=c*16+(lane&15)] = We[n][k]); blocks 200..212
// convert W[100][200] -> Wf fragments (K padded to 224, N to 112, zero-filled).
// ---------------------------------------------------------------------------
__global__ __launch_bounds__(256) void prep(const float* __restrict__ We,
                                            const float* __restrict__ W,
                                            half_t* __restrict__ Bf,
                                            half_t* __restrict__ Wf) {
  if (blockIdx.x < 200) {
    int t = blockIdx.x * 256 + threadIdx.x;  // 100 n x 512 kp
    int n = t >> 9;
    int kp = t & 511;
    int k0 = kp * 8;
    int ks = k0 >> 5;
    int q = (k0 >> 3) & 3;
    int c = n >> 4, m = n & 15;
    int lane = q * 16 + m;
    const float* src = We + (size_t)n * 4096 + k0;
    half8 hv, lv;
#pragma unroll
    for (int j = 0; j < 8; ++j) {
      float w = src[j];
      half_t hh = (half_t)w;
      hv[j] = hh; lv[j] = (half_t)(w - (float)hh);
    }
    size_t base = (size_t)(ks * 14 + c * 2) * 64 + lane;
    *(half8*)(Bf + base * 8) = hv;
    *(half8*)(Bf + (base + 64) * 8) = lv;
  } else {
    int u = (blockIdx.x - 200) * 256 + threadIdx.x;  // 49 frag-pairs x 64 lanes
    if (u >= 3136) return;
    int fb = u >> 6, lane = u & 63;
    int ks = fb / 7, tt = fb % 7;
    int q = lane >> 4, n = lane & 15;
    int col = tt * 16 + n;
    int kb = ks * 32 + q * 8;
    half8 hv, lv;
#pragma unroll
    for (int j = 0; j < 8; ++j) {
      int k = kb + j;
      float w = (col < 100 && k < 200) ? W[(size_t)col * 200 + k] : 0.f;
      half_t hh = (half_t)w;
      hv[j] = hh; lv[j] = (half_t)(w - (float)hh);
    }
    size_t base = (size_t)(ks * 14 + tt * 2) * 64 + lane;
    *(half8*)(Wf + base * 8) = hv;
    *(half8*)(Wf + (base + 64) * 8) = lv;
  }
}

// ---------------------------------------------------------------------------
// leaf_mfma: partial h0p[kh][row][col] = sum_{k in half kh} A[row][k]*We[col][k].
// 512 blocks x 256 thr (4 waves): block = (row-tile rt = b>>1: rows rt*32..+32) x
// (K-half kh = b&1). 8 chunks of BK=256, double-buffered LDS (2 blocks/CU).
// Waves split N: wave w -> col-tiles {2w, 2w+1} (wave 3: tile 6 only). No k-reduce.
// ---------------------------------------------------------------------------
__global__ __launch_bounds__(256, 2) void leaf_mfma(const float* __restrict__ A,
                                                    const half8* __restrict__ Bf,
                                                    float* __restrict__ h0p) {
  __shared__ __align__(16) float lds[2 * 8320];  // 2 bufs x 32 rows x 260 floats = 66,560 B
  const int tid = threadIdx.x;
  const int lane = tid & 63;
  const int wave = tid >> 6;
  const int q = lane >> 4, m = lane & 15;
  const int rt = blockIdx.x >> 1;
  const int kh = blockIdx.x & 1;
  const int r0 = rt * 32;
  const int t0 = 2 * wave;
  const int t1 = (2 * wave + 1 < 7) ? (2 * wave + 1) : 6;
  const bool two = (t1 != t0);

  floatx4 acc[2][2];
#pragma unroll
  for (int a = 0; a < 2; ++a)
#pragma unroll
    for (int c = 0; c < 2; ++c) acc[a][c] = (floatx4){0.f, 0.f, 0.f, 0.f};

  // wave stages rows [w*8, w*8+8); one gld_lds16 = 64 lanes x 16 B = one 1 KB row-chunk
  const float* gbase = A + (size_t)(r0 + wave * 8) * 4096 + (size_t)kh * 2048 + lane * 4;
  const int ldso = (wave * 8) * 260 + lane * 4;

#pragma unroll
  for (int i = 0; i < 8; ++i) gld_lds16(gbase + (size_t)i * 4096, lds + ldso + i * 260);
  __syncthreads();

  for (int t = 0; t < 8; ++t) {
    // All B frags for this chunk FIRST (oldest in vmcnt queue): consuming them
    // waits only down to the staging count, never draining the async staging.
    half8 bh[8][2], bl[8][2];
    const int ksgb = kh * 64 + t * 8;
#pragma unroll
    for (int k = 0; k < 8; ++k) {
      const half8* bb = Bf + (size_t)((ksgb + k) * 14) * 64 + lane;
      bh[k][0] = bb[(t0 * 2) * 64];
      bl[k][0] = bb[(t0 * 2 + 1) * 64];
      if (two) {
        bh[k][1] = bb[(t1 * 2) * 64];
        bl[k][1] = bb[(t1 * 2 + 1) * 64];
      }
    }
    __builtin_amdgcn_sched_barrier(0);  // pin B loads before the staging instrs

    if (t < 7) {  // async-stage next chunk into the other buffer
      const float* g = gbase + (t + 1) * 256;
      float* d = lds + ((t + 1) & 1) * 8320 + ldso;
#pragma unroll
      for (int i = 0; i < 8; ++i) gld_lds16(g + (size_t)i * 4096, d + i * 260);
    }

    const float* cur = lds + (t & 1) * 8320;
#pragma unroll
    for (int k = 0; k < 8; ++k) {
      const float* ap = cur + m * 260 + k * 32 + q * 8;
      floatx4 a0 = *(const floatx4*)ap;
      floatx4 a1 = *(const floatx4*)(ap + 4);
      floatx4 a2 = *(const floatx4*)(ap + 16 * 260);
      floatx4 a3 = *(const floatx4*)(ap + 16 * 260 + 4);
      half8 ah0, al0, ah1, al1;
      cvt_hilo(a0, a1, ah0, al0);
      cvt_hilo(a2, a3, ah1, al1);
      acc[0][0] = __builtin_amdgcn_mfma_f32_16x16x32_f16(ah0, bh[k][0], acc[0][0], 0, 0, 0);
      acc[1][0] = __builtin_amdgcn_mfma_f32_16x16x32_f16(ah1, bh[k][0], acc[1][0], 0, 0, 0);
      acc[0][0] = __builtin_amdgcn_mfma_f32_16x16x32_f16(al0, bh[k][0], acc[0][0], 0, 0, 0);
      acc[1][0] = __builtin_amdgcn_mfma_f32_16x16x32_f16(al1, bh[k][0], acc[1][0], 0, 0, 0);
      acc[0][0] = __builtin_amdgcn_mfma_f32_16x16x32_f16(ah0, bl[k][0], acc[0][0], 0, 0, 0);
      acc[1][0] = __builtin_amdgcn_mfma_f32_16x16x32_f16(ah1, bl[k][0], acc[1][0], 0, 0, 0);
      if (two) {
        acc[0][1] = __builtin_amdgcn_mfma_f32_16x16x32_f16(ah0, bh[k][1], acc[0][1], 0, 0, 0);
        acc[1][1] = __builtin_amdgcn_mfma_f32_16x16x32_f16(ah1, bh[k][1], acc[1][1], 0, 0, 0);
        acc[0][1] = __builtin_amdgcn_mfma_f32_16x16x32_f16(al0, bh[k][1], acc[0][1], 0, 0, 0);
        acc[1][1] = __builtin_amdgcn_mfma_f32_16x16x32_f16(al1, bh[k][1], acc[1][1], 0, 0, 0);
        acc[0][1] = __builtin_amdgcn_mfma_f32_16x16x32_f16(ah0, bl[k][1], acc[0][1], 0, 0, 0);
        acc[1][1] = __builtin_amdgcn_mfma_f32_16x16x32_f16(ah1, bl[k][1], acc[1][1], 0, 0, 0);
      }
    }
    __syncthreads();
  }

  // Epilogue: direct partial stores (C/D layout: col=lane&15, row=q*4+reg).
  const size_t part = (size_t)kh * H0ROWS;
#pragma unroll
  for (int tt = 0; tt < 2; ++tt) {
#pragma unroll
    for (int r = 0; r < 4; ++r) {
      int row = r0 + tt * 16 + q * 4 + r;
      float* o = h0p + part + (size_t)row * 112;
      o[t0 * 16 + m] = acc[tt][0][r];
      if (two) o[t1 * 16 + m] = acc[tt][1][r];
    }
  }
}

// ---------------------------------------------------------------------------
// tree_mfma: block takes NVEC consecutive 100-vectors -> log2(NVEC) levels -> 1 vector.
// Level GEMM: out[row][col] = relu(b[col] + sum_k pair[row][k]*W[col][k]), K=200->224.
// 4 waves; wave w covers col-tiles {2w, min(2w+1,6)}; W fragments in VGPRs.
// SUMIN: input is the two leaf partial buffers (stride 112); apply +be and relu at load.
// PROJ: final kernel also computes the 2 logits.
// ---------------------------------------------------------------------------
template <int NVEC, bool PROJ, bool SUMIN>
__global__ __launch_bounds__(256, 1) void tree_mfma(const float* __restrict__ in,
                                                    float* __restrict__ out,
                                                    const half8* __restrict__ Wf,
                                                    const float* __restrict__ bt,
                                                    const float* __restrict__ be,
                                                    const float* __restrict__ Wp,
                                                    const float* __restrict__ bp) {
  __shared__ __align__(16) float bufA[16 * 228];
  __shared__ __align__(16) float bufB[16 * 228];
  const int tid = threadIdx.x;
  const int lane = tid & 63;
  const int wave = tid >> 6;
  const int q = lane >> 4, m = lane & 15;
  const int t0 = 2 * wave;
  const int t1 = (2 * wave + 1 > 6) ? 6 : 2 * wave + 1;

  half8 wh0[7], wl0[7], wh1[7], wl1[7];
#pragma unroll
  for (int ks = 0; ks < 7; ++ks) {
    wh0[ks] = Wf[(size_t)(ks * 14 + t0 * 2) * 64 + lane];
    wl0[ks] = Wf[(size_t)(ks * 14 + t0 * 2 + 1) * 64 + lane];
    wh1[ks] = Wf[(size_t)(ks * 14 + t1 * 2) * 64 + lane];
    wl1[ks] = Wf[(size_t)(ks * 14 + t1 * 2 + 1) * 64 + lane];
  }
  const int c0 = t0 * 16 + m;
  const int c1 = t1 * 16 + m;
  const float b0 = (c0 < 100) ? bt[c0] : 0.f;
  const float b1 = (c1 < 100) ? bt[c1] : 0.f;

  for (int i = tid; i < 16 * 228; i += 256) { bufA[i] = 0.f; bufB[i] = 0.f; }
  __syncthreads();
  if (SUMIN) {
    const size_t gb = (size_t)blockIdx.x * NVEC * 112;
    for (int i = tid; i < NVEC * 100; i += 256) {
      int v = i / 100, j = i - v * 100;
      float x = fmaxf(in[gb + (size_t)v * 112 + j] + in[H0ROWS + gb + (size_t)v * 112 + j] + be[j], 0.f);
      bufA[(v >> 1) * 228 + (v & 1) * 100 + j] = x;
    }
  } else {
    const float* gin = in + (size_t)blockIdx.x * NVEC * 100;
    for (int i = tid; i < NVEC * 100; i += 256) {
      int v = i / 100, j = i - v * 100;
      bufA[(v >> 1) * 228 + (v & 1) * 100 + j] = gin[i];
    }
  }
  __syncthreads();

  float* src = bufA;
  float* dst = bufB;
  constexpr int L = (NVEC == 32) ? 5 : 3;
#pragma unroll
  for (int l = 0; l < L; ++l) {
    const int nout = NVEC >> (l + 1);
    floatx4 acc0 = (floatx4){0.f, 0.f, 0.f, 0.f};
    floatx4 acc1 = (floatx4){0.f, 0.f, 0.f, 0.f};
#pragma unroll
    for (int ks = 0; ks < 7; ++ks) {
      const float* ap = src + m * 228 + ks * 32 + q * 8;
      floatx4 x0 = *(const floatx4*)ap;
      floatx4 x1 = *(const floatx4*)(ap + 4);
      half8 ah, al;
      cvt_hilo(x0, x1, ah, al);
      acc0 = __builtin_amdgcn_mfma_f32_16x16x32_f16(ah, wh0[ks], acc0, 0, 0, 0);
      acc1 = __builtin_amdgcn_mfma_f32_16x16x32_f16(ah, wh1[ks], acc1, 0, 0, 0);
      acc0 = __builtin_amdgcn_mfma_f32_16x16x32_f16(al, wh0[ks], acc0, 0, 0, 0);
      acc1 = __builtin_amdgcn_mfma_f32_16x16x32_f16(al, wh1[ks], acc1, 0, 0, 0);
      acc0 = __builtin_amdgcn_mfma_f32_16x16x32_f16(ah, wl0[ks], acc0, 0, 0, 0);
      acc1 = __builtin_amdgcn_mfma_f32_16x16x32_f16(ah, wl1[ks], acc1, 0, 0, 0);
    }
#pragma unroll
    for (int r = 0; r < 4; ++r) {
      int rowR = q * 4 + r;
      if (rowR < nout) {
        if (c0 < 100)
          dst[(rowR >> 1) * 228 + (rowR & 1) * 100 + c0] = fmaxf(acc0[r] + b0, 0.f);
        if (t1 != t0 && c1 < 100)
          dst[(rowR >> 1) * 228 + (rowR & 1) * 100 + c1] = fmaxf(acc1[r] + b1, 0.f);
      }
    }
    __syncthreads();
    float* tmp = src; src = dst; dst = tmp;
  }
  if (PROJ) {
    if (tid < 128) {
      int cls = tid >> 6, l = tid & 63;
      float sum = Wp[cls * 100 + l] * src[l];
      if (l + 64 < 100) sum += Wp[cls * 100 + l + 64] * src[l + 64];
#pragma unroll
      for (int off = 32; off > 0; off >>= 1) sum += __shfl_down(sum, off, 64);
      if (l == 0) out[cls] = sum + bp[cls];
    }
  } else {
    if (tid < 100) out[(size_t)blockIdx.x * 100 + tid] = src[tid];
  }
}

extern "C" void kernel_launch(void* const* d_in, const int* in_sizes, int n_in,
                              void* d_out, int out_size, void* d_ws, size_t ws_size,
                              hipStream_t stream) {
  (void)in_sizes; (void)n_in; (void)out_size; (void)ws_size;
  const float* leaf = (const float*)d_in[0];  // [8192][4096]
  const float* We = (const float*)d_in[1];    // [100][4096]
  const float* be = (const float*)d_in[2];    // [100]
  const float* W = (const float*)d_in[3];     // [100][200]
  const float* b = (const float*)d_in[4];     // [100]
  const float* Wp = (const float*)d_in[5];    // [2][100]
  const float* bp = (const float*)d_in[6];    // [2]
  float* out = (float*)d_out;                 // [2]

  char* ws = (char*)d_ws;
  half_t* Bf = (half_t*)ws;                        // 1792 frags * 1 KB = 1,835,008 B
  half_t* Wfr = (half_t*)(ws + 1835008);           // 98 frags * 1 KB = 100,352 B
  float* h0p = (float*)(ws + 1935360);             // 2 x 8192 x 112 fp32 = 7,340,032 B
  float* h1 = (float*)(ws + 9275392);              // 256*100*4
  float* h2 = (float*)(ws + 9377792);              // 8*100*4

  prep<<<dim3(213), dim3(256), 0, stream>>>(We, W, Bf, Wfr);
  leaf_mfma<<<dim3(512), dim3(256), 0, stream>>>(leaf, (const half8*)Bf, h0p);
  tree_mfma<32, false, true><<<dim3(256), dim3(256), 0, stream>>>(h0p, h1, (const half8*)Wfr, b, be, nullptr, nullptr);
  tree_mfma<32, false, false><<<dim3(8), dim3(256), 0, stream>>>(h1, h2, (const half8*)Wfr, b, nullptr, nullptr, nullptr);
  tree_mfma<8, true, false><<<dim3(1), dim3(256), 0, stream>>>(h2, out, (const half8*)Wfr, b, nullptr, Wp, bp);
}